// Round 1
// baseline (1047.576 us; speedup 1.0000x reference)
//
#include <hip/hip_runtime.h>

#define TPB 256

constexpr int Cc  = 64;    // C
constexpr int CRc = 16;    // C*R
constexpr int Sc  = 32;    // S
constexpr int O1c = 2048;  // 2*C*CR
constexpr int Nn  = 4096;  // N
constexpr int PT  = 8;     // points per block
constexpr float EPSf = 1e-5f;

__device__ __forceinline__ float bf2f(unsigned short u) {
    union { unsigned int i; float f; } x; x.i = ((unsigned int)u) << 16; return x.f;
}
__device__ __forceinline__ unsigned short f2bf(float f) {
    union { float f; unsigned int i; } x; x.f = f;
    unsigned int r = x.i + 0x7fffu + ((x.i >> 16) & 1u);
    return (unsigned short)(r >> 16);
}

__global__ __launch_bounds__(TPB, 2) void dyn_fused(
    const float* __restrict__ pre, const float* __restrict__ feat,
    const float* __restrict__ w1,
    const float* __restrict__ bn1g, const float* __restrict__ bn1b,
    const float* __restrict__ bn1m, const float* __restrict__ bn1v,
    const float* __restrict__ ln1g, const float* __restrict__ ln1b,
    const float* __restrict__ ln2g, const float* __restrict__ ln2b,
    const float* __restrict__ w2,
    const float* __restrict__ bn2g, const float* __restrict__ bn2b,
    const float* __restrict__ bn2m, const float* __restrict__ bn2v,
    float* __restrict__ out)
{
    __shared__ float          fL[Cc][PT];        // features tile, [c][j]
    __shared__ unsigned short hL[PT][O1c];       // bf16 h (dynamic params), [j][o]
    __shared__ unsigned short flatL[PT][O1c];    // bf16 flat (stage-B output), [j][k]
    __shared__ float          preL[Sc][Cc + 1];  // pre tile for current point, [s][c]
    __shared__ float          t1L[Sc][CRc + 1];  // post-LN1 t1, [s][r]

    const int tid = threadIdx.x;
    const int p0  = blockIdx.x * PT;
    const int b   = p0 >> 12;          // N = 4096
    const int n0  = p0 & (Nn - 1);

    // load features tile fL[c][j]
    for (int idx = tid; idx < Cc * PT; idx += TPB) {
        int c = idx >> 3, j = idx & 7;
        fL[c][j] = feat[((size_t)(b * Cc + c)) * Nn + n0 + j];
    }
    __syncthreads();

    // ---------------- Stage A: h = relu(bn1(w1 @ f)) -> hL bf16 ----------------
    {
        float acc[8][PT];
        #pragma unroll
        for (int oi = 0; oi < 8; ++oi)
            #pragma unroll
            for (int j = 0; j < PT; ++j) acc[oi][j] = 0.f;

        for (int c4 = 0; c4 < Cc / 4; ++c4) {
            float fv[4][PT];
            #pragma unroll
            for (int q = 0; q < 4; ++q)
                #pragma unroll
                for (int j = 0; j < PT; ++j) fv[q][j] = fL[c4 * 4 + q][j];
            #pragma unroll
            for (int oi = 0; oi < 8; ++oi) {
                float4 w = *reinterpret_cast<const float4*>(
                    w1 + (size_t)(oi * TPB + tid) * Cc + c4 * 4);
                #pragma unroll
                for (int j = 0; j < PT; ++j)
                    acc[oi][j] += w.x * fv[0][j] + w.y * fv[1][j]
                                + w.z * fv[2][j] + w.w * fv[3][j];
            }
        }
        #pragma unroll
        for (int oi = 0; oi < 8; ++oi) {
            int o = oi * TPB + tid;
            float inv = bn1g[o] * rsqrtf(bn1v[o] + EPSf);
            float sh  = bn1b[o] - bn1m[o] * inv;
            #pragma unroll
            for (int j = 0; j < PT; ++j)
                hL[j][o] = f2bf(fmaxf(acc[oi][j] * inv + sh, 0.f));
        }
    }
    __syncthreads();

    // ---------------- Stage B: per-point dynamic interaction ----------------
    for (int jj = 0; jj < PT; ++jj) {
        // load pre tile [s][c] for point (b, n0+jj); element = pre[((b*C+c)*N+n)*S+s]
        const float* pbase = pre + ((size_t)b * Cc * Nn + n0 + jj) * Sc;
        for (int idx = tid; idx < Cc * Sc / 4; idx += TPB) {
            int c = idx >> 3, s4 = idx & 7;
            float4 v = *reinterpret_cast<const float4*>(pbase + (size_t)c * Nn * Sc + s4 * 4);
            preL[s4 * 4 + 0][c] = v.x;
            preL[s4 * 4 + 1][c] = v.y;
            preL[s4 * 4 + 2][c] = v.z;
            preL[s4 * 4 + 3][c] = v.w;
        }
        __syncthreads();

        // t1[s][r] = relu(ln1(sum_c pre[s][c] * param1[c][r])), param1[c][r]=h[c*16+r]
        {
            int r = tid & 15, s = tid >> 4;   // each thread: rows s and s+16
            const unsigned short* hrow = hL[jj];
            float a0 = 0.f, a1 = 0.f;
            for (int c = 0; c < Cc; ++c) {
                float pv = bf2f(hrow[c * CRc + r]);
                a0 += preL[s][c]      * pv;
                a1 += preL[s + 16][c] * pv;
            }
            float s0 = a0, s1 = a1, q0 = a0 * a0, q1 = a1 * a1;
            #pragma unroll
            for (int m = 1; m < 16; m <<= 1) {
                s0 += __shfl_xor(s0, m, 16);
                s1 += __shfl_xor(s1, m, 16);
                q0 += __shfl_xor(q0, m, 16);
                q1 += __shfl_xor(q1, m, 16);
            }
            float mu0 = s0 * 0.0625f, mu1 = s1 * 0.0625f;
            float v0 = q0 * 0.0625f - mu0 * mu0;
            float v1 = q1 * 0.0625f - mu1 * mu1;
            float g = ln1g[r], bb = ln1b[r];
            t1L[s][r]      = fmaxf((a0 - mu0) * rsqrtf(v0 + EPSf) * g + bb, 0.f);
            t1L[s + 16][r] = fmaxf((a1 - mu1) * rsqrtf(v1 + EPSf) * g + bb, 0.f);
        }
        __syncthreads();

        // t2[s][c] = relu(ln2(sum_r t1[s][r] * param2[r][c])), param2[r][c]=h[1024+r*64+c]
        // one wave = one row of 64 channels; LN2 via full-wave shuffle reduce
        {
            int c = tid & 63, w = tid >> 6;
            const unsigned short* hrow = hL[jj] + Cc * CRc;
            float g = ln2g[c], bb = ln2b[c];
            for (int i = 0; i < 8; ++i) {
                int s = w * 8 + i;
                float a = 0.f;
                #pragma unroll
                for (int r2 = 0; r2 < CRc; ++r2)
                    a += t1L[s][r2] * bf2f(hrow[r2 * Cc + c]);
                float sm = a, sq = a * a;
                #pragma unroll
                for (int m = 1; m < 64; m <<= 1) {
                    sm += __shfl_xor(sm, m, 64);
                    sq += __shfl_xor(sq, m, 64);
                }
                float mu = sm * 0.015625f;
                float vv = sq * 0.015625f - mu * mu;
                float vout = fmaxf((a - mu) * rsqrtf(vv + EPSf) * g + bb, 0.f);
                flatL[jj][s * Cc + c] = f2bf(vout);   // k = s*64 + c
            }
        }
        // no sync needed here: next-iter writes are fenced by the two syncs above
    }
    __syncthreads();

    // ---------------- Stage C: y = relu(bn2(w2 @ flat)); out = relu(y + f) ----------------
    {
        int o = tid >> 2, jq = tid & 3;      // thread owns (o, jq) and (o, jq+4)
        float a0 = 0.f, a1 = 0.f;
        const float4* w2r = reinterpret_cast<const float4*>(w2 + (size_t)o * O1c);
        const unsigned short* f0 = flatL[jq];
        const unsigned short* f1 = flatL[jq + 4];
        for (int k4 = 0; k4 < O1c / 4; ++k4) {
            float4 w = w2r[k4];
            int k = k4 * 4;
            a0 += w.x * bf2f(f0[k])     + w.y * bf2f(f0[k + 1])
                + w.z * bf2f(f0[k + 2]) + w.w * bf2f(f0[k + 3]);
            a1 += w.x * bf2f(f1[k])     + w.y * bf2f(f1[k + 1])
                + w.z * bf2f(f1[k + 2]) + w.w * bf2f(f1[k + 3]);
        }
        float inv = bn2g[o] * rsqrtf(bn2v[o] + EPSf);
        float sh  = bn2b[o] - bn2m[o] * inv;
        float y0 = fmaxf(a0 * inv + sh, 0.f);
        float y1 = fmaxf(a1 * inv + sh, 0.f);
        size_t obase = ((size_t)(b * Cc + o)) * Nn + n0;
        out[obase + jq]     = fmaxf(y0 + fL[o][jq], 0.f);
        out[obase + jq + 4] = fmaxf(y1 + fL[o][jq + 4], 0.f);
    }
}

extern "C" void kernel_launch(void* const* d_in, const int* in_sizes, int n_in,
                              void* d_out, int out_size, void* d_ws, size_t ws_size,
                              hipStream_t stream) {
    (void)in_sizes; (void)n_in; (void)out_size; (void)d_ws; (void)ws_size;
    const float* pre  = (const float*)d_in[0];
    const float* feat = (const float*)d_in[1];
    const float* w1   = (const float*)d_in[2];
    const float* bn1g = (const float*)d_in[3];
    const float* bn1b = (const float*)d_in[4];
    const float* bn1m = (const float*)d_in[5];
    const float* bn1v = (const float*)d_in[6];
    const float* ln1g = (const float*)d_in[7];
    const float* ln1b = (const float*)d_in[8];
    const float* ln2g = (const float*)d_in[9];
    const float* ln2b = (const float*)d_in[10];
    const float* w2   = (const float*)d_in[11];
    const float* bn2g = (const float*)d_in[12];
    const float* bn2b = (const float*)d_in[13];
    const float* bn2m = (const float*)d_in[14];
    const float* bn2v = (const float*)d_in[15];
    float* out = (float*)d_out;

    dim3 grid(32768 / PT), block(TPB);
    dyn_fused<<<grid, block, 0, stream>>>(pre, feat, w1,
        bn1g, bn1b, bn1m, bn1v, ln1g, ln1b, ln2g, ln2b,
        w2, bn2g, bn2b, bn2m, bn2v, out);
}

// Round 2
// 379.980 us; speedup vs baseline: 2.7569x; 2.7569x over previous
//
#include <hip/hip_runtime.h>

typedef __attribute__((ext_vector_type(8))) short short8;
typedef __attribute__((ext_vector_type(4))) float f32x4;

#define TPB 256
constexpr float EPSf = 1e-5f;

__device__ __forceinline__ unsigned short f2bf(float f) {
    union { float f; unsigned int i; } x; x.f = f;
    unsigned int r = x.i + 0x7fffu + ((x.i >> 16) & 1u);
    return (unsigned short)(r >> 16);
}

// ---------------- LDS layout (byte offsets), all hot reads <=2-way via XOR slots ---------
// flat_t :     0 .. 32767   [8 pt][2048 k] bf16, slot = (pt&7)^((k>>6)&7)
// p1t    : 32768 .. 49151   [8 pt][16 r][64 c] bf16 (param1^T), slot = (r&7)^(pt&7)
// p2t    : 49152 .. 65535   [8 pt][64 c][16 r] bf16 (param2^T), slot = ((c>>2)&1)^(pt&7)
// preB   : 65536 .. 73727   [4 w][32 s][32 cc] bf16 (half-K pre tile), slot = s&7
// t1B    : 73728 .. 77823   [4 w][32 s][16 r] bf16 (t1^T), slot = (s>>2)&1
// fbfT   : 77824 .. 79871   [16 pt][64 c] bf16 (rows 8-15 zero), slot = pt&7
__device__ __forceinline__ int FTa(int pt, int k) {
    return pt*4096 + ((k*2) ^ ((((pt&7) ^ ((k>>6)&7))) << 4));
}
__device__ __forceinline__ int P1a(int pt, int r, int c) {
    return 32768 + pt*2048 + ((r*128 + c*2) ^ ((((r&7) ^ (pt&7))) << 4));
}
__device__ __forceinline__ int P2a(int pt, int c, int r) {
    return 49152 + pt*2048 + ((c*32 + r*2) ^ (((((c>>2)&1) ^ (pt&7))) << 4));
}
__device__ __forceinline__ int PRa(int w, int s, int cc) {
    return 65536 + w*2048 + ((s*64 + cc*2) ^ ((s&7) << 4));
}
__device__ __forceinline__ int T1a(int w, int s, int r) {
    return 73728 + w*1024 + ((s*32 + r*2) ^ (((s>>2)&1) << 4));
}
__device__ __forceinline__ int FBa(int pt, int c) {
    return 77824 + pt*128 + ((c*2) ^ ((pt&7) << 4));
}

// ---- prep: fold BN into bf16 weights ----
__global__ void prep_kernel(const float* __restrict__ w1,
                            const float* __restrict__ g1, const float* __restrict__ b1,
                            const float* __restrict__ m1, const float* __restrict__ v1,
                            const float* __restrict__ w2,
                            const float* __restrict__ g2, const float* __restrict__ b2,
                            const float* __restrict__ m2, const float* __restrict__ v2,
                            unsigned short* __restrict__ w1s, unsigned short* __restrict__ w2s,
                            float* __restrict__ sh1, float* __restrict__ sh2) {
    int i = blockIdx.x * TPB + threadIdx.x;
    if (i < 2048*64) {
        int o = i >> 6;
        float inv = g1[o] * rsqrtf(v1[o] + EPSf);
        w1s[i] = f2bf(w1[i] * inv);
        int o2 = i >> 11;
        float inv2 = g2[o2] * rsqrtf(v2[o2] + EPSf);
        w2s[i] = f2bf(w2[i] * inv2);
    }
    if (i < 2048) sh1[i] = b1[i] - m1[i] * (g1[i] * rsqrtf(v1[i] + EPSf));
    if (i < 64)   sh2[i] = b2[i] - m2[i] * (g2[i] * rsqrtf(v2[i] + EPSf));
}

__global__ __launch_bounds__(TPB, 2) void dyn_mfma(
    const float* __restrict__ pre, const float* __restrict__ feat,
    const unsigned short* __restrict__ w1s, const unsigned short* __restrict__ w2s,
    const float* __restrict__ sh1, const float* __restrict__ sh2,
    const float* __restrict__ ln1g, const float* __restrict__ ln1b,
    const float* __restrict__ ln2g, const float* __restrict__ ln2b,
    float* __restrict__ out)
{
    __shared__ __align__(16) unsigned char smem[79872];
    unsigned short* sm16 = (unsigned short*)smem;

    const int tid = threadIdx.x;
    const int w   = tid >> 6;   // wave 0..3
    const int l   = tid & 63;
    const int lr  = l & 15;     // MFMA row/col lane
    const int g   = l >> 4;     // k-group 0..3

    const int p0 = blockIdx.x * 8;
    const int b  = p0 >> 12;
    const int n0 = p0 & 4095;

    // ---- prologue: features -> fbfT bf16 ([pt][c]); zero pad rows 8..15 ----
    for (int idx = tid; idx < 512; idx += TPB) {
        int c = idx >> 3, pt = idx & 7;
        float fv = feat[((size_t)(b*64 + c))*4096 + n0 + pt];
        sm16[FBa(pt, c) >> 1] = f2bf(fv);
    }
    for (int idx = tid; idx < 512; idx += TPB) {
        int pt = 8 + (idx >> 6), c = idx & 63;
        sm16[FBa(pt, c) >> 1] = 0;
    }
    // per-lane LN params (r = g*4+q for LN1; c = mt*16+g*4+q for LN2)
    float ln1gv[4], ln1bv[4];
    #pragma unroll
    for (int q = 0; q < 4; ++q) { ln1gv[q] = ln1g[g*4 + q]; ln1bv[q] = ln1b[g*4 + q]; }
    float ln2gv[4][4], ln2bv[4][4];
    #pragma unroll
    for (int mt = 0; mt < 4; ++mt)
        #pragma unroll
        for (int q = 0; q < 4; ++q) {
            ln2gv[mt][q] = ln2g[mt*16 + g*4 + q];
            ln2bv[mt][q] = ln2b[mt*16 + g*4 + q];
        }
    __syncthreads();

    // ---------------- Stage A: h = relu(w1s @ f + sh1) -> p1t/p2t ----------------
    {
        short8 bfA[2];
        bfA[0] = *(const short8*)&smem[FBa(lr, g*8)];
        bfA[1] = *(const short8*)&smem[FBa(lr, 32 + g*8)];
        #pragma unroll 2
        for (int i = 0; i < 32; ++i) {
            const int m0 = (w*32 + i) * 16;
            short8 a0 = *(const short8*)(w1s + (size_t)(m0 + lr)*64 + g*8);
            short8 a1 = *(const short8*)(w1s + (size_t)(m0 + lr)*64 + 32 + g*8);
            f32x4 acc = {0.f, 0.f, 0.f, 0.f};
            acc = __builtin_amdgcn_mfma_f32_16x16x32_bf16(a0, bfA[0], acc, 0, 0, 0);
            acc = __builtin_amdgcn_mfma_f32_16x16x32_bf16(a1, bfA[1], acc, 0, 0, 0);
            f32x4 shv = *(const f32x4*)(sh1 + m0 + g*4);
            if (lr < 8) {
                #pragma unroll
                for (int q = 0; q < 4; ++q) {
                    int o = m0 + g*4 + q;
                    unsigned short hb = f2bf(fmaxf(acc[q] + shv[q], 0.f));
                    if (o < 1024) sm16[P1a(lr, o & 15, o >> 4) >> 1] = hb;           // param1[c][r]=h[c*16+r]
                    else { int o2 = o - 1024; sm16[P2a(lr, o2 & 63, o2 >> 6) >> 1] = hb; } // param2[r][c]=h[1024+r*64+c]
                }
            }
        }
    }
    __syncthreads();

    // ---------------- Stage B: per-point dynamic GEMMs (transposed) ----------------
    #pragma unroll 1
    for (int pp = 0; pp < 2; ++pp) {
        const int pt = w*2 + pp;
        const float* pbase = pre + (size_t)b*64*4096*32 + (size_t)(n0 + pt)*32;

        // GEMM1: t1^T[r][s] = sum_c param1^T[r][c] * pre^T[c][s], K=64 in 2 halves
        f32x4 acc1[2] = {{0,0,0,0},{0,0,0,0}};
        #pragma unroll 1
        for (int kk = 0; kk < 2; ++kk) {
            #pragma unroll
            for (int i = 0; i < 4; ++i) {          // stage 32c x 32s half into preB (wave-private)
                int cc = i*8 + (l >> 3);
                int s4 = l & 7;
                float4 v = *(const float4*)(pbase + (size_t)(kk*32 + cc)*131072 + s4*4);
                sm16[PRa(w, s4*4+0, cc) >> 1] = f2bf(v.x);
                sm16[PRa(w, s4*4+1, cc) >> 1] = f2bf(v.y);
                sm16[PRa(w, s4*4+2, cc) >> 1] = f2bf(v.z);
                sm16[PRa(w, s4*4+3, cc) >> 1] = f2bf(v.w);
            }
            // wave-private RAW: DS ops are in-order; compiler inserts lgkmcnt waits
            short8 a  = *(const short8*)&smem[P1a(pt, lr, kk*32 + g*8)];
            short8 b0 = *(const short8*)&smem[PRa(w, lr,      g*8)];
            short8 b1 = *(const short8*)&smem[PRa(w, 16 + lr, g*8)];
            acc1[0] = __builtin_amdgcn_mfma_f32_16x16x32_bf16(a, b0, acc1[0], 0, 0, 0);
            acc1[1] = __builtin_amdgcn_mfma_f32_16x16x32_bf16(a, b1, acc1[1], 0, 0, 0);
        }
        // LN1 over r (M-dim): in-lane 4 regs + xor16 + xor32
        #pragma unroll
        for (int nt = 0; nt < 2; ++nt) {
            float sm = acc1[nt][0] + acc1[nt][1] + acc1[nt][2] + acc1[nt][3];
            float sq = acc1[nt][0]*acc1[nt][0] + acc1[nt][1]*acc1[nt][1]
                     + acc1[nt][2]*acc1[nt][2] + acc1[nt][3]*acc1[nt][3];
            sm += __shfl_xor(sm, 16); sm += __shfl_xor(sm, 32);
            sq += __shfl_xor(sq, 16); sq += __shfl_xor(sq, 32);
            float mu = sm * 0.0625f;
            float rs = rsqrtf(sq * 0.0625f - mu*mu + EPSf);
            int s = nt*16 + lr;
            #pragma unroll
            for (int q = 0; q < 4; ++q) {
                float v = fmaxf((acc1[nt][q] - mu) * rs * ln1gv[q] + ln1bv[q], 0.f);
                sm16[T1a(w, s, g*4 + q) >> 1] = f2bf(v);
            }
        }
        // GEMM2: t2^T[c][s] = sum_r param2^T[c][r] * t1^T[r][s], K=16 padded to 32
        short8 z8 = {};
        short8 bf2[2];
        #pragma unroll
        for (int nt = 0; nt < 2; ++nt) {
            bf2[nt] = z8;
            if (g < 2) bf2[nt] = *(const short8*)&smem[T1a(w, nt*16 + lr, g*8)];
        }
        f32x4 zac = {0,0,0,0};
        f32x4 acc2[4][2];
        #pragma unroll
        for (int mt = 0; mt < 4; ++mt) {
            short8 af = z8;
            if (g < 2) af = *(const short8*)&smem[P2a(pt, mt*16 + lr, g*8)];
            #pragma unroll
            for (int nt = 0; nt < 2; ++nt)
                acc2[mt][nt] = __builtin_amdgcn_mfma_f32_16x16x32_bf16(af, bf2[nt], zac, 0, 0, 0);
        }
        // LN2 over c (M-dim, 64): in-lane 16 + xor16 + xor32; then relu -> flat_t
        #pragma unroll
        for (int nt = 0; nt < 2; ++nt) {
            float sm = 0.f, sq = 0.f;
            #pragma unroll
            for (int mt = 0; mt < 4; ++mt)
                #pragma unroll
                for (int q = 0; q < 4; ++q) { float v = acc2[mt][nt][q]; sm += v; sq += v*v; }
            sm += __shfl_xor(sm, 16); sm += __shfl_xor(sm, 32);
            sq += __shfl_xor(sq, 16); sq += __shfl_xor(sq, 32);
            float mu = sm * 0.015625f;
            float rs = rsqrtf(sq * 0.015625f - mu*mu + EPSf);
            int s = nt*16 + lr;
            #pragma unroll
            for (int mt = 0; mt < 4; ++mt)
                #pragma unroll
                for (int q = 0; q < 4; ++q) {
                    float v = fmaxf((acc2[mt][nt][q] - mu) * rs * ln2gv[mt][q] + ln2bv[mt][q], 0.f);
                    int k = s*64 + mt*16 + g*4 + q;
                    sm16[FTa(pt, k) >> 1] = f2bf(v);
                }
        }
    }
    __syncthreads();

    // ---------------- Stage C: out = relu(relu(w2s@flat + sh2) + feat) ----------------
    {
        const int m0 = w * 16;
        f32x4 accA = {0,0,0,0}, accB = {0,0,0,0};
        #pragma unroll 4
        for (int ks = 0; ks < 64; ks += 2) {
            short8 a0 = *(const short8*)(w2s + (size_t)(m0 + lr)*2048 + ks*32 + g*8);
            short8 b0 = *(const short8*)&smem[FTa(lr, ks*32 + g*8)];        // lr>=8: harmless garbage cols
            short8 a1 = *(const short8*)(w2s + (size_t)(m0 + lr)*2048 + (ks+1)*32 + g*8);
            short8 b1 = *(const short8*)&smem[FTa(lr, (ks+1)*32 + g*8)];
            accA = __builtin_amdgcn_mfma_f32_16x16x32_bf16(a0, b0, accA, 0, 0, 0);
            accB = __builtin_amdgcn_mfma_f32_16x16x32_bf16(a1, b1, accB, 0, 0, 0);
        }
        f32x4 shv = *(const f32x4*)(sh2 + m0 + g*4);
        if (lr < 8) {
            #pragma unroll
            for (int q = 0; q < 4; ++q) {
                int o = m0 + g*4 + q;
                float y = fmaxf(accA[q] + accB[q] + shv[q], 0.f);
                size_t oidx = ((size_t)(b*64 + o))*4096 + n0 + lr;
                out[oidx] = fmaxf(y + feat[oidx], 0.f);
            }
        }
    }
}

extern "C" void kernel_launch(void* const* d_in, const int* in_sizes, int n_in,
                              void* d_out, int out_size, void* d_ws, size_t ws_size,
                              hipStream_t stream) {
    (void)in_sizes; (void)n_in; (void)out_size; (void)ws_size;
    const float* pre  = (const float*)d_in[0];
    const float* feat = (const float*)d_in[1];
    const float* w1   = (const float*)d_in[2];
    const float* bn1g = (const float*)d_in[3];
    const float* bn1b = (const float*)d_in[4];
    const float* bn1m = (const float*)d_in[5];
    const float* bn1v = (const float*)d_in[6];
    const float* ln1g = (const float*)d_in[7];
    const float* ln1b = (const float*)d_in[8];
    const float* ln2g = (const float*)d_in[9];
    const float* ln2b = (const float*)d_in[10];
    const float* w2   = (const float*)d_in[11];
    const float* bn2g = (const float*)d_in[12];
    const float* bn2b = (const float*)d_in[13];
    const float* bn2m = (const float*)d_in[14];
    const float* bn2v = (const float*)d_in[15];
    float* out = (float*)d_out;

    unsigned short* w1s = (unsigned short*)d_ws;          // 2048*64 bf16
    unsigned short* w2s = w1s + 2048*64;                  // 64*2048 bf16
    float* sh1 = (float*)(w2s + 64*2048);                 // 2048 f32
    float* sh2 = sh1 + 2048;                              // 64 f32

    prep_kernel<<<512, TPB, 0, stream>>>(w1, bn1g, bn1b, bn1m, bn1v,
                                         w2, bn2g, bn2b, bn2m, bn2v,
                                         w1s, w2s, sh1, sh2);
    dyn_mfma<<<4096, TPB, 0, stream>>>(pre, feat, w1s, w2s, sh1, sh2,
                                       ln1g, ln1b, ln2g, ln2b, out);
}

// Round 3
// 190.489 us; speedup vs baseline: 5.4994x; 1.9948x over previous
//
#include <hip/hip_runtime.h>
#include <hip/hip_bf16.h>

typedef __attribute__((ext_vector_type(8)))  short short8;
typedef __attribute__((ext_vector_type(4)))  float f32x4;
typedef __attribute__((ext_vector_type(16))) float f32x16;

constexpr float EPSf = 1e-5f;

__device__ __forceinline__ unsigned short f2bf(float f) {
    union { float f; unsigned int i; } x; x.f = f;
    unsigned int r = x.i + 0x7fffu + ((x.i >> 16) & 1u);
    return (unsigned short)(r >> 16);
}
__device__ __forceinline__ unsigned int pk2bf(float lo, float hi) {
    union { __hip_bfloat162 h; unsigned int u; } z;
    z.h = __float22bfloat162_rn(make_float2(lo, hi));
    return z.u;
}

// ---------------- LDS layout (byte offsets) ----------------
// FLAT 0..32767      [8 pt][2048 k] bf16, XOR slot (pt^(k>>6))&7
// P1   32768..49151  [8 pt][16 r][64 c] bf16 (param1^T)
// P2   49152..65535  [8 pt][64 c][16 r] bf16 (param2^T)
// T1   65536..73727  [8 w][32 s][16 r] bf16 (t1^T, wave-private)
// FBF  73728..75775  [16 pt][64 c] bf16 (rows 8-15 zero)
// LN2  75776..76287  [g 64 | b 64] f32
// PART 32768..65535  [8 w][16 ptc][64 o] f32 (overlays P1+P2, stage C)
__device__ __forceinline__ int FTa(int pt, int k) {
    return pt*4096 + ((k*2) ^ (((pt ^ (k>>6)) & 7) << 4));
}
__device__ __forceinline__ int P1a(int pt, int r, int c) {
    return 32768 + pt*2048 + ((r*128 + c*2) ^ (((r ^ pt) & 7) << 4));
}
__device__ __forceinline__ int P2a(int pt, int c, int r) {
    return 49152 + pt*2048 + ((c*32 + r*2) ^ (((((c>>2)&1) ^ (pt&7))) << 4));
}
__device__ __forceinline__ int T1a(int w, int s, int r) {
    return 65536 + w*1024 + s*32 + r*2;
}
__device__ __forceinline__ int FBa(int pt, int c) {
    return 73728 + pt*128 + ((c*2) ^ ((pt&7) << 4));
}
__device__ __forceinline__ int PTa(int w, int ptc, int o) {
    return 32768 + w*4096 + ptc*256 + ((o*4) ^ ((ptc&3) << 5));
}

// ---- prep: fold BN into bf16 weights, in MFMA-fragment-linear order ----
__global__ void prep_kernel(const float* __restrict__ w1,
                            const float* __restrict__ g1, const float* __restrict__ b1,
                            const float* __restrict__ m1, const float* __restrict__ v1,
                            const float* __restrict__ w2,
                            const float* __restrict__ g2, const float* __restrict__ b2,
                            const float* __restrict__ m2, const float* __restrict__ v2,
                            unsigned short* __restrict__ w1f, unsigned short* __restrict__ w2f,
                            float* __restrict__ sh1, float* __restrict__ sh2) {
    int idx = blockIdx.x * 256 + threadIdx.x;
    if (idx < 2048*64) {
        // w1f: A-frag for stage A: (o,c) -> [(i*2+kk)*64 + lane]*8 + j
        int o = idx >> 6, c = idx & 63;
        float inv = g1[o] * rsqrtf(v1[o] + EPSf);
        int i = o >> 4, kk = c >> 5, gg = (c >> 3) & 3, j = c & 7;
        w1f[(((i*2 + kk)*64) + gg*16 + (o & 15))*8 + j] = f2bf(w1[idx] * inv);
        // w2f: A-frag for stage C: (o2,k) -> [(ks*4+mt)*64 + lane]*8 + j
        int o2 = idx >> 11, k = idx & 2047;
        float inv2 = g2[o2] * rsqrtf(v2[o2] + EPSf);
        int ks = k >> 5, mt = o2 >> 4, gk = (k >> 3) & 3, j2 = k & 7;
        w2f[(((ks*4 + mt)*64) + gk*16 + (o2 & 15))*8 + j2] = f2bf(w2[idx] * inv2);
    }
    if (idx < 2048) sh1[idx] = b1[idx] - m1[idx] * (g1[idx] * rsqrtf(v1[idx] + EPSf));
    if (idx < 64)   sh2[idx] = b2[idx] - m2[idx] * (g2[idx] * rsqrtf(v2[idx] + EPSf));
}

__global__ __launch_bounds__(512, 4) void dyn_mfma(
    const float* __restrict__ pre, const float* __restrict__ feat,
    const unsigned short* __restrict__ w1f, const unsigned short* __restrict__ w2f,
    const float* __restrict__ sh1, const float* __restrict__ sh2,
    const float* __restrict__ ln1g, const float* __restrict__ ln1b,
    const float* __restrict__ ln2g, const float* __restrict__ ln2b,
    float* __restrict__ out)
{
    __shared__ __align__(16) unsigned char smem[76288];
    unsigned short* sm16 = (unsigned short*)smem;

    const int tid = threadIdx.x;
    const int w  = tid >> 6, l = tid & 63;
    const int lr = l & 15, g = l >> 4;      // 16-lane MFMA frame
    const int c32 = l & 31, hi = l >> 5;    // 32-lane MFMA frame

    const int p0 = blockIdx.x * 8;
    const int b  = p0 >> 12, n0 = p0 & 4095;
    const int pt = w;                        // this wave's stage-B point

    // ---- prefetch 1: pre fragments for this wave's point (32 dwords, HBM) ----
    const float* pbase = pre + (size_t)b*8388608 + (size_t)(n0 + pt)*32;
    float pf[2][2][8];
    #pragma unroll
    for (int kk = 0; kk < 2; ++kk)
        #pragma unroll
        for (int nt = 0; nt < 2; ++nt)
            #pragma unroll
            for (int j = 0; j < 8; ++j)
                pf[kk][nt][j] = pbase[(size_t)(kk*32 + g*8 + j)*131072 + nt*16 + lr];

    // ---- prefetch 2: residual feature for the final epilogue ----
    const int ro = tid >> 3, rp = tid & 7;
    const size_t oidx = ((size_t)(b*64 + ro))*4096 + n0 + rp;
    const float fres = feat[oidx];

    // ---- prologue: features -> FBF bf16; LN2 coefs -> LDS ----
    {
        int c = tid >> 3, pj = tid & 7;
        float fv = feat[((size_t)(b*64 + c))*4096 + n0 + pj];
        sm16[FBa(pj, c) >> 1] = f2bf(fv);
        sm16[FBa(8 + (tid >> 6), tid & 63) >> 1] = 0;   // zero pad rows 8..15
        float* lnf = (float*)(smem + 75776);
        if (tid < 64)       lnf[tid] = ln2g[tid];
        else if (tid < 128) lnf[tid] = ln2b[tid - 64];
    }
    __syncthreads();

    const f32x4 zz4 = {0.f, 0.f, 0.f, 0.f};
    const f32x16 zz16 = {};

    // ---------------- Stage A: h = relu(w1f @ f + sh1) -> P1/P2 ----------------
    {
        short8 bf0 = *(const short8*)&smem[FBa(lr, g*8)];
        short8 bf1 = *(const short8*)&smem[FBa(lr, 32 + g*8)];
        const unsigned short* w1p = w1f + ((size_t)(w*32)*64 + l)*8;
        #pragma unroll 4
        for (int ii = 0; ii < 16; ++ii) {
            short8 a0 = *(const short8*)(w1p + (ii*2 + 0)*512);
            short8 a1 = *(const short8*)(w1p + (ii*2 + 1)*512);
            f32x4 acc = __builtin_amdgcn_mfma_f32_16x16x32_bf16(a0, bf0, zz4, 0, 0, 0);
            acc = __builtin_amdgcn_mfma_f32_16x16x32_bf16(a1, bf1, acc, 0, 0, 0);
            const int i = w*16 + ii;
            f32x4 shv = *(const f32x4*)(sh1 + i*16 + g*4);
            if (lr < 8) {
                if (w < 4) {           // o<1024: param1[c=i][r=g*4+q]
                    #pragma unroll
                    for (int q = 0; q < 4; ++q)
                        sm16[P1a(lr, g*4 + q, i) >> 1] = f2bf(fmaxf(acc[q] + shv[q], 0.f));
                } else {               // o>=1024: param2[r][c]
                    const int i2 = i - 64;
                    const int r  = i2 >> 2;
                    const int cb = (i2 & 3)*16 + g*4;
                    #pragma unroll
                    for (int q = 0; q < 4; ++q)
                        sm16[P2a(lr, cb + q, r) >> 1] = f2bf(fmaxf(acc[q] + shv[q], 0.f));
                }
            }
        }
    }
    __syncthreads();

    // ---------------- Stage B: per-point dynamic GEMMs (1 pt per wave) ----------------
    {
        // convert prefetched pre to bf16 B-fragments
        short8 pb[2][2];
        #pragma unroll
        for (int kk = 0; kk < 2; ++kk)
            #pragma unroll
            for (int nt = 0; nt < 2; ++nt) {
                union { unsigned int u[4]; short8 s; } z;
                #pragma unroll
                for (int d = 0; d < 4; ++d)
                    z.u[d] = pk2bf(pf[kk][nt][2*d], pf[kk][nt][2*d + 1]);
                pb[kk][nt] = z.s;
            }
        // GEMM1: t1^T[r][s] = p1^T[r][c] @ pre^T[c][s], K=64
        short8 a1f0 = *(const short8*)&smem[P1a(pt, lr, g*8)];
        short8 a1f1 = *(const short8*)&smem[P1a(pt, lr, 32 + g*8)];
        f32x4 acc1[2];
        #pragma unroll
        for (int nt = 0; nt < 2; ++nt) {
            f32x4 a = __builtin_amdgcn_mfma_f32_16x16x32_bf16(a1f0, pb[0][nt], zz4, 0, 0, 0);
            acc1[nt] = __builtin_amdgcn_mfma_f32_16x16x32_bf16(a1f1, pb[1][nt], a, 0, 0, 0);
        }
        // LN1 over r: in-lane 4 + shfl(16,32); coefs per-lane from global
        f32x4 l1g = *(const f32x4*)(ln1g + g*4);
        f32x4 l1b = *(const f32x4*)(ln1b + g*4);
        #pragma unroll
        for (int nt = 0; nt < 2; ++nt) {
            float s0 = acc1[nt][0] + acc1[nt][1] + acc1[nt][2] + acc1[nt][3];
            float q0 = acc1[nt][0]*acc1[nt][0] + acc1[nt][1]*acc1[nt][1]
                     + acc1[nt][2]*acc1[nt][2] + acc1[nt][3]*acc1[nt][3];
            s0 += __shfl_xor(s0, 16); s0 += __shfl_xor(s0, 32);
            q0 += __shfl_xor(q0, 16); q0 += __shfl_xor(q0, 32);
            float mu = s0 * 0.0625f;
            float rs = rsqrtf(q0 * 0.0625f - mu*mu + EPSf);
            float v0 = fmaxf((acc1[nt][0] - mu)*rs*l1g[0] + l1b[0], 0.f);
            float v1 = fmaxf((acc1[nt][1] - mu)*rs*l1g[1] + l1b[1], 0.f);
            float v2 = fmaxf((acc1[nt][2] - mu)*rs*l1g[2] + l1b[2], 0.f);
            float v3 = fmaxf((acc1[nt][3] - mu)*rs*l1g[3] + l1b[3], 0.f);
            uint2 dd; dd.x = pk2bf(v0, v1); dd.y = pk2bf(v2, v3);
            *(uint2*)&smem[T1a(w, nt*16 + lr, g*4)] = dd;
        }
        // GEMM2 (32x32x16): t2^T[c][s] = p2^T[c][r] @ t1^T[r][s], K=16 exact
        short8 bt1  = *(const short8*)&smem[T1a(w, c32, hi*8)];
        short8 a2f0 = *(const short8*)&smem[P2a(pt, c32, hi*8)];
        short8 a2f1 = *(const short8*)&smem[P2a(pt, 32 + c32, hi*8)];
        f32x16 acc2a = __builtin_amdgcn_mfma_f32_32x32x16_bf16(a2f0, bt1, zz16, 0, 0, 0);
        f32x16 acc2b = __builtin_amdgcn_mfma_f32_32x32x16_bf16(a2f1, bt1, zz16, 0, 0, 0);
        // LN2 over c (64): in-lane 32 + one shfl(32) pair
        float sm2 = 0.f, sq2 = 0.f;
        #pragma unroll
        for (int e = 0; e < 16; ++e) { float v = acc2a[e]; sm2 += v; sq2 += v*v; }
        #pragma unroll
        for (int e = 0; e < 16; ++e) { float v = acc2b[e]; sm2 += v; sq2 += v*v; }
        sm2 += __shfl_xor(sm2, 32); sq2 += __shfl_xor(sq2, 32);
        float mu2 = sm2 * (1.0f/64.0f);
        float rs2 = rsqrtf(sq2 * (1.0f/64.0f) - mu2*mu2 + EPSf);
        const float* lnf = (const float*)(smem + 75776);
        // tile 0 (c = 0..31)
        #pragma unroll
        for (int qh = 0; qh < 4; ++qh) {
            int c0 = qh*8 + hi*4;
            f32x4 gq = *(const f32x4*)&lnf[c0];
            f32x4 bq = *(const f32x4*)&lnf[64 + c0];
            float t0 = fmaxf((acc2a[qh*4 + 0] - mu2)*rs2*gq[0] + bq[0], 0.f);
            float t1 = fmaxf((acc2a[qh*4 + 1] - mu2)*rs2*gq[1] + bq[1], 0.f);
            float t2 = fmaxf((acc2a[qh*4 + 2] - mu2)*rs2*gq[2] + bq[2], 0.f);
            float t3 = fmaxf((acc2a[qh*4 + 3] - mu2)*rs2*gq[3] + bq[3], 0.f);
            uint2 dd; dd.x = pk2bf(t0, t1); dd.y = pk2bf(t2, t3);
            *(uint2*)&smem[FTa(pt, c32*64 + c0)] = dd;
        }
        // tile 1 (c = 32..63)
        #pragma unroll
        for (int qh = 0; qh < 4; ++qh) {
            int c0 = 32 + qh*8 + hi*4;
            f32x4 gq = *(const f32x4*)&lnf[c0];
            f32x4 bq = *(const f32x4*)&lnf[64 + c0];
            float t0 = fmaxf((acc2b[qh*4 + 0] - mu2)*rs2*gq[0] + bq[0], 0.f);
            float t1 = fmaxf((acc2b[qh*4 + 1] - mu2)*rs2*gq[1] + bq[1], 0.f);
            float t2 = fmaxf((acc2b[qh*4 + 2] - mu2)*rs2*gq[2] + bq[2], 0.f);
            float t3 = fmaxf((acc2b[qh*4 + 3] - mu2)*rs2*gq[3] + bq[3], 0.f);
            uint2 dd; dd.x = pk2bf(t0, t1); dd.y = pk2bf(t2, t3);
            *(uint2*)&smem[FTa(pt, c32*64 + c0)] = dd;
        }
    }
    __syncthreads();

    // ---------------- Stage C: k-split w2f @ flat, partials -> LDS reduce ----------------
    {
        f32x4 acc[4] = {zz4, zz4, zz4, zz4};
        #pragma unroll 2
        for (int t = 0; t < 8; ++t) {
            const int ks = w*8 + t;
            short8 bfl = *(const short8*)&smem[FTa(lr, ks*32 + g*8)];
            const unsigned short* w2p = w2f + ((size_t)(ks*4)*64 + l)*8;
            #pragma unroll
            for (int mt = 0; mt < 4; ++mt) {
                short8 af = *(const short8*)(w2p + mt*512);
                acc[mt] = __builtin_amdgcn_mfma_f32_16x16x32_bf16(af, bfl, acc[mt], 0, 0, 0);
            }
        }
        #pragma unroll
        for (int mt = 0; mt < 4; ++mt)
            *((f32x4*)&smem[PTa(w, lr, mt*16 + g*4)]) = acc[mt];
    }
    __syncthreads();
    // reduce 8 partials; epilogue: relu(bn2-affine) + residual relu
    {
        float s = 0.f;
        #pragma unroll
        for (int ww = 0; ww < 8; ++ww)
            s += *(const float*)&smem[PTa(ww, rp, ro)];
        float y = fmaxf(s + sh2[ro], 0.f);
        out[oidx] = fmaxf(y + fres, 0.f);
    }
}

extern "C" void kernel_launch(void* const* d_in, const int* in_sizes, int n_in,
                              void* d_out, int out_size, void* d_ws, size_t ws_size,
                              hipStream_t stream) {
    (void)in_sizes; (void)n_in; (void)out_size; (void)ws_size;
    const float* pre  = (const float*)d_in[0];
    const float* feat = (const float*)d_in[1];
    const float* w1   = (const float*)d_in[2];
    const float* bn1g = (const float*)d_in[3];
    const float* bn1b = (const float*)d_in[4];
    const float* bn1m = (const float*)d_in[5];
    const float* bn1v = (const float*)d_in[6];
    const float* ln1g = (const float*)d_in[7];
    const float* ln1b = (const float*)d_in[8];
    const float* ln2g = (const float*)d_in[9];
    const float* ln2b = (const float*)d_in[10];
    const float* w2   = (const float*)d_in[11];
    const float* bn2g = (const float*)d_in[12];
    const float* bn2b = (const float*)d_in[13];
    const float* bn2m = (const float*)d_in[14];
    const float* bn2v = (const float*)d_in[15];
    float* out = (float*)d_out;

    unsigned short* w1f = (unsigned short*)d_ws;          // 2048*64 bf16
    unsigned short* w2f = w1f + 2048*64;                  // 64*2048 bf16
    float* sh1 = (float*)(w2f + 64*2048);                 // 2048 f32
    float* sh2 = sh1 + 2048;                              // 64 f32

    prep_kernel<<<512, 256, 0, stream>>>(w1, bn1g, bn1b, bn1m, bn1v,
                                         w2, bn2g, bn2b, bn2m, bn2v,
                                         w1f, w2f, sh1, sh2);
    dyn_mfma<<<4096, 512, 0, stream>>>(pre, feat, w1f, w2f, sh1, sh2,
                                       ln1g, ln1b, ln2g, ln2b, out);
}